// Round 3
// baseline (208.059 us; speedup 1.0000x reference)
//
#include <hip/hip_runtime.h>

#define M1 81
#define MSZ 80
#define NEL (M1 * M1)          // 6561
#define NTW ((NEL + 31) / 32)  // 206 words of target bits
#define NACC 12
#define BIGKC 1.0e30f

typedef __attribute__((address_space(1))) const void* gas_t;
typedef __attribute__((address_space(3))) void* las_t;

// accumulator indices:
// 0 target_num, 1 n_pre, 2 n_next, 3 n_union,
// 4 s_pre, 5 s_next, 6 s_all, 7 s_sim,
// 8 s_acc_pre, 9 s_acc_next, 10 n_mpre, 11 n_mnext

__global__ __launch_bounds__(512, 8) void sst_main(
    const float* __restrict__ input,
    const int* __restrict__ target,
    const int* __restrict__ mask0,
    const int* __restrict__ mask1,
    float* __restrict__ out,       // [7] scalars; out+7 = idx [slices*80]
    float* __restrict__ part,      // AoS: part[slice*NACC + k]
    int slices,
    unsigned* counter)             // nullptr -> two-kernel fallback
{
    __shared__ __align__(16) float s_xraw[NEL + 4];  // x staged; e after sweep A
    __shared__ unsigned s_tb[NTW];      // target bits, row-major
    __shared__ float s_m0[M1], s_m1[M1];
    __shared__ float s_kc[M1];          // log(csum) (1e30 sentinel @80)
    __shared__ float s_invc[M1];        // 1/csum (0 sentinel @80 for argmax)
    __shared__ float s_pA[486];         // sweepA csum partials
    __shared__ float s_pC[480];         // sweepB rsum partials
    __shared__ float s_pV[486];         // argmax value partials (A: col, C: row)
    __shared__ unsigned char s_pI[486]; // argmax index partials
    __shared__ unsigned char s_pT[486]; // first-target partials (127 = none)
    __shared__ unsigned char s_ci[MSZ]; // per-column argmax row (from B-merge)
    __shared__ int s_ct[MSZ];           // per-column first target row (atomicMin)
    __shared__ unsigned s_m1w[4];       // m1 bitmask (bit c = mask1[c] != 0)
    __shared__ float s_wv[8][8][NACC];  // 3-stage reduce partials
    __shared__ int s_lastf;

    const int tid   = threadIdx.x;
    const int lane  = tid & 63;
    const int w     = tid >> 6;
    const int slice = blockIdx.x;
    const size_t base = (size_t)slice * NEL;

    // slice base (in floats) is ≡ slice (mod 4); shift LDS base so both the
    // global float4 pointer and the LDS destination are 16B aligned.
    float* sx = s_xraw + (slice & 3);
    const int h = (4 - (slice & 3)) & 3;      // scalar head elements

    if (tid < M1) s_m0[tid] = (float)mask0[slice * M1 + tid];
    else if (tid >= 128 && tid < 128 + M1) s_m1[tid - 128] = (float)mask1[slice * M1 + (tid - 128)];
    if (tid >= 256 && tid < 256 + MSZ) s_ct[tid - 256] = 0x7fffffff;

    float a[NACC];
#pragma unroll
    for (int k = 0; k < NACC; ++k) a[k] = 0.0f;

    // ---- staging: direct global->LDS DMA (lane pattern = base + lane*16) ----
    if (tid < h) sx[tid] = input[base + tid];
    const float4* in4 = (const float4*)(input + base + h);
#pragma unroll
    for (int it = 0; it < 3; ++it) {          // 1536 float4s, full waves only
        const int i = tid + (it << 9);
        __builtin_amdgcn_global_load_lds((gas_t)(in4 + i),
                                         (las_t)(sx + h + (i << 2)), 16, 0, 0);
    }
    {   // tail floats [h+6144, NEL): at most 417, one strided round
        const int i = h + 6144 + tid;
        if (i < NEL) sx[i] = input[base + i];
    }
    __syncthreads();   // B1 (drains DMA + scalar staging)

    // target prefetch AFTER B1: the 26KB fetch flies under sweep A's compute
    // (before B1 it would be drained by B1's vmcnt(0) and hide nothing).
    int tpre[13];
#pragma unroll
    for (int k = 0; k < 13; ++k) {
        const int i = tid + (k << 9);
        tpre[k] = (i < NEL) ? target[base + i] : 0;
    }

    // m1 bit windows (consumed in sweep C, after B3)
    if (w == 0) {
        const unsigned long long m = __ballot(s_m1[lane] != 0.0f);
        if (lane == 0) { s_m1w[0] = (unsigned)m; s_m1w[1] = (unsigned)(m >> 32); }
    } else if (w == 1) {
        float v = 0.0f;
        if (lane < 17) v = s_m1[64 + lane];
        const unsigned long long m = __ballot(v != 0.0f);
        if (lane == 0) { s_m1w[2] = (unsigned)m; s_m1w[3] = 0u; }
    }

    // ---- sweep A: columns (81 cols x 6 threads); store e = exp(m1c*m0r*x) ----
    if (tid < 486) {
        const int c = tid / 6, j = tid - 6 * (tid / 6);
        const int r0 = j * 13 + ((j < 3) ? j : 3);
        const int len = (j < 3) ? 14 : 13;
        const float m1c = s_m1[c];
        float cs = 0.0f, bv = -1.0f;
        int bi = r0;
        int idx = r0 * M1 + c;
        for (int i = 0; i < len; ++i, idx += M1) {
            const int r = r0 + i;
            const float z = m1c * s_m0[r] * sx[idx];
            const float e = __expf(z);
            sx[idx] = e;                      // same-thread overwrite: race-free
            cs += e;
            if (e > bv) { bv = e; bi = r; }   // first-max (ascending r)
        }
        s_pA[tid] = cs; s_pV[tid] = bv; s_pI[tid] = (unsigned char)bi;
    }

    // ---- target bit-pack (prefetched regs -> ballot -> s_tb) + target_num ----
#pragma unroll
    for (int k = 0; k < 13; ++k) {
        const int i = tid + (k << 9);
        if (i < NEL) {
            const unsigned long long m = __ballot(tpre[k] != 0);
            if (lane == 0) {
                a[0] += (float)__popcll(m);
                const int w2 = (i >> 5) & ~1;
                s_tb[w2] = (unsigned)m;
                if (w2 + 1 < NTW) s_tb[w2 + 1] = (unsigned)(m >> 32);
            }
        }
    }
    __syncthreads();   // B2

    // ---- sweep B (row e-sums, no exp) | column merge (tids 480..511) ----
    if (tid < 480) {
        const int r = tid / 6, j = tid - 6 * (tid / 6);
        const int c0 = j * 13 + ((j < 3) ? j : 3);
        const int len = (j < 3) ? 14 : 13;
        const int rb = r * M1 + c0;
        float rs = 0.0f;
        for (int i = 0; i < len; ++i) rs += sx[rb + i];
        s_pC[tid] = rs;
    } else {
        const int u = tid - 480;
        for (int c = u; c < M1; c += 32) {
            if (c < MSZ) {
                const int b = 6 * c;
                float cs = 0.0f;
#pragma unroll
                for (int k = 0; k < 6; ++k) cs += s_pA[b + k];
                float bv = s_pV[b]; int bi = s_pI[b];
#pragma unroll
                for (int k = 1; k < 6; ++k) {
                    const float v = s_pV[b + k];
                    if (v > bv) { bv = v; bi = s_pI[b + k]; }  // first-max
                }
                s_kc[c] = __logf(cs);
                s_invc[c] = 1.0f / cs;
                s_ci[c] = (unsigned char)bi;
            } else {
                s_kc[c] = BIGKC;     // col-80: pre-only in min(lr,kc)
                s_invc[c] = 0.0f;    // col-80: argmax uses e*invr only
            }
        }
    }
    __syncthreads();   // B3

    // ---- sweep C: rows 0..79 (tids 0..479) + row-80 next-terms (480..485) ----
    if (tid < 480) {
        const int r = tid / 6, j = tid - 6 * (tid / 6);
        const int c0 = j * 13 + ((j < 3) ? j : 3);
        const int len = (j < 3) ? 14 : 13;
        const int rb = r * M1;
        const int pb = 6 * r;
        const float rs = s_pC[pb] + s_pC[pb + 1] + s_pC[pb + 2]
                       + s_pC[pb + 3] + s_pC[pb + 4] + s_pC[pb + 5];
        const float lr = __logf(rs), invr = 1.0f / rs;
        const float m0f = s_m0[r];

        // bit window: t & m1 & m0 over cols [c0, c0+len)
        const int bp = rb + c0;
        const unsigned long long tw64 =
            ((unsigned long long)s_tb[(bp >> 5) + 1] << 32) | s_tb[bp >> 5];
        const int mp0 = c0 >> 5;
        const unsigned long long mw64 =
            ((unsigned long long)s_m1w[mp0 + 1] << 32) | s_m1w[mp0];
        const unsigned lenmask = (1u << len) - 1u;
        unsigned wb = (unsigned)(tw64 >> (bp & 31)) & (unsigned)(mw64 >> (c0 & 31)) & lenmask;
        if (m0f == 0.0f) wb = 0u;

        const unsigned w3 = (j == 5) ? (wb & 0x0FFFu) : wb;  // drop c=80 bit
        a[1] += (float)__popc(wb);   // n_pre
        a[2] += (float)__popc(w3);   // n_next (rows<80 part)
        a[3] += (float)__popc(w3);   // n_union
        const int ti = wb ? (c0 + __ffs(wb) - 1) : 127;

        // row argmax of input_all = e * max(invr, invc)  (linear domain,
        // structurally identical to reference max(input_pre, input_next))
        float bv = -1.0f; int bi = c0;
        for (int i = 0; i < len; ++i) {
            const int c = c0 + i;
            const float val = sx[rb + c] * fmaxf(invr, s_invc[c]);
            if (val > bv) { bv = val; bi = c; }   // strict >, ascending: first-max
        }
        // sparse t-terms (z recovered by logf; ~1.7 bits/thread avg)
        unsigned wl = wb;
        while (wl) {
            const int b = __ffs(wl) - 1; wl &= wl - 1u;
            const int c = c0 + b;
            const float e = sx[rb + c];
            const float z = __logf(e);
            a[4] += lr - z;                              // s_pre
            a[6] += fminf(lr, s_kc[c]) - z;              // s_all (c=80: min=lr)
            if (c != MSZ) {
                a[5] += s_kc[c] - z;                     // s_next (rows<80 part)
                a[7] = fmaf(e, fabsf(s_invc[c] - invr), a[7]);  // sim (union)
                atomicMin(&s_ct[c], r);                  // first target row / col
            }
        }
        s_pV[tid] = bv; s_pI[tid] = (unsigned char)bi; s_pT[tid] = (unsigned char)ti;
    } else if (tid < 486) {
        // row 80: only n_next / s_next / ct terms survive
        const int j = tid - 480;
        const int c0 = j * 13 + ((j < 3) ? j : 3);
        const int len = (j < 3) ? 14 : 13;
        const int rb = MSZ * M1;
        const float m80 = s_m0[MSZ];
        const int bp = rb + c0;
        const unsigned long long tw64 =
            ((unsigned long long)s_tb[(bp >> 5) + 1] << 32) | s_tb[bp >> 5];
        const int mp0 = c0 >> 5;
        const unsigned long long mw64 =
            ((unsigned long long)s_m1w[mp0 + 1] << 32) | s_m1w[mp0];
        const unsigned lenmask = (1u << len) - 1u;
        unsigned wb = (unsigned)(tw64 >> (bp & 31)) & (unsigned)(mw64 >> (c0 & 31)) & lenmask;
        if (m80 == 0.0f) wb = 0u;
        if (j == 5) wb &= 0x0FFFu;                       // next-mask zeroes col 80
        a[2] += (float)__popc(wb);
        while (wb) {
            const int b = __ffs(wb) - 1; wb &= wb - 1u;
            const int c = c0 + b;
            a[5] += s_kc[c] - __logf(sx[rb + c]);
            atomicMin(&s_ct[c], MSZ);
        }
    }
    __syncthreads();   // B4

    if (tid < MSZ) {   // merge row argmax + accuracy_pre
        const int b = 6 * tid;
        float bv = s_pV[b]; int bi = s_pI[b];
#pragma unroll
        for (int k = 1; k < 6; ++k) {
            const float v = s_pV[b + k];
            if (v > bv) { bv = v; bi = s_pI[b + k]; }
        }
        int ti = 127;
#pragma unroll
        for (int k = 0; k < 6; ++k) ti = min(ti, (int)s_pT[b + k]);
        if (ti == 127) ti = 0;
        out[7 + (size_t)slice * MSZ + tid] = (float)bi;
        const float m0f = s_m0[tid];
        a[8]  += (bi == ti) ? m0f : 0.0f;
        a[10] += m0f;
    } else if (tid >= 128 && tid < 128 + MSZ) {   // accuracy_next (cols 0..79)
        const int c = tid - 128;
        const int ctv = s_ct[c];
        const int ti = (ctv == 0x7fffffff) ? 0 : ctv;
        const int bi = (int)s_ci[c];
        const float m1c = s_m1[c];
        a[9]  += (bi == ti) ? m1c : 0.0f;
        a[11] += m1c;
    }

    // ---- block reduce: 3-stage shuffle (64 -> 8 lanes) -> LDS -> AoS part ----
    float red[NACC];
#pragma unroll
    for (int k = 0; k < NACC; ++k) {
        float v = a[k];
        v += __shfl_down(v, 32);
        v += __shfl_down(v, 16);
        v += __shfl_down(v, 8);
        red[k] = v;
    }
    if (lane < 8) {
#pragma unroll
        for (int k = 0; k < NACC; ++k) s_wv[w][lane][k] = red[k];
    }
    __syncthreads();   // B5
    if (tid < NACC) {
        float s = 0.0f;
        const float* sv = (const float*)s_wv;
#pragma unroll 8
        for (int m = 0; m < 64; ++m) s += sv[m * NACC + tid];
        part[(size_t)slice * NACC + tid] = s;   // one 48B burst per block
    }

    // ---- fused final reduction: last block to arrive does it ----
    // Counter is NEVER initialized: winner test is (old+1) % slices == 0,
    // which fires exactly once per launch for ANY starting value (poisoned
    // workspace ok) and stays correct across graph replays (monotone counter;
    // 2^32 % 2048 == 0 so wraparound is exact for power-of-two slice counts).
    if (counter) {
        if (w == 0) __threadfence();            // release: wave 0 holds the 12 storers
        __syncthreads();   // B6
        if (tid == 0) {
            const unsigned old = atomicAdd(counter, 1u);   // device scope
            s_lastf = (((old + 1u) % (unsigned)slices) == 0u) ? 1 : 0;
        }
        __syncthreads();   // B7
        if (s_lastf) {
            __threadfence();                    // acquire: see all blocks' parts
            double l[NACC];
#pragma unroll
            for (int k = 0; k < NACC; ++k) l[k] = 0.0;
            for (int s = tid; s < slices; s += 512) {
                const float* p = part + (size_t)s * NACC;
#pragma unroll
                for (int k = 0; k < NACC; ++k) l[k] += (double)p[k];
            }
            double* sd = (double*)s_xraw;       // s_x dead after sweep C
#pragma unroll
            for (int k = 0; k < NACC; ++k) {
                double v = l[k];
                for (int off = 32; off > 0; off >>= 1) v += __shfl_down(v, off);
                if (lane == 0) sd[w * NACC + k] = v;
            }
            __syncthreads();   // B8
            if (tid == 0) {
                double g[NACC];
#pragma unroll
                for (int k = 0; k < NACC; ++k) {
                    double s = 0.0;
                    for (int ww = 0; ww < 8; ++ww) s += sd[ww * NACC + k];
                    g[k] = s;
                }
                const double tnum = g[0], npre = g[1], nnext = g[2], nunion = g[3];
                const double spre = g[4], snext = g[5], sall = g[6], ssim = g[7];
                const double accp = g[8], accn = g[9], nmp = g[10], nmn = g[11];
                const double loss_pre  = (npre > 0.0) ? spre / npre : spre;
                const double loss_next = (nnext > 0.0) ? snext / nnext : snext;
                const double loss      = (npre > 0.0 && nnext > 0.0) ? sall / npre : sall;
                const double loss_sim  = (nunion > 0.0) ? ssim / tnum : ssim;
                const double total = (loss_pre + loss_next + loss + loss_sim) * 0.25;
                const double ap = (nmp > 0.0) ? accp / nmp : accp + 1.0;
                const double an = (nmn > 0.0) ? accn / nmn : accn + 1.0;
                out[0] = (float)loss_pre;
                out[1] = (float)loss_next;
                out[2] = (float)loss_sim;
                out[3] = (float)total;
                out[4] = (float)ap;
                out[5] = (float)an;
                out[6] = (float)((ap + an) * 0.5);
            }
        }
    }
}

// fallback when workspace can't hold the counter (kept for safety)
__global__ __launch_bounds__(256) void sst_final(
    const float* __restrict__ part, int slices, float* __restrict__ out)
{
    __shared__ double s_part[4][NACC];
    const int tid = threadIdx.x;
    double l[NACC];
#pragma unroll
    for (int k = 0; k < NACC; ++k) l[k] = 0.0;
    for (int s = tid; s < slices; s += 256) {
        const float* p = part + (size_t)s * NACC;
#pragma unroll
        for (int k = 0; k < NACC; ++k) l[k] += (double)p[k];
    }
#pragma unroll
    for (int k = 0; k < NACC; ++k) {
        double v = l[k];
        for (int off = 32; off > 0; off >>= 1) v += __shfl_down(v, off);
        if ((tid & 63) == 0) s_part[tid >> 6][k] = v;
    }
    __syncthreads();
    if (tid == 0) {
        double g[NACC];
#pragma unroll
        for (int k = 0; k < NACC; ++k)
            g[k] = s_part[0][k] + s_part[1][k] + s_part[2][k] + s_part[3][k];
        const double tnum = g[0], npre = g[1], nnext = g[2], nunion = g[3];
        const double spre = g[4], snext = g[5], sall = g[6], ssim = g[7];
        const double accp = g[8], accn = g[9], nmp = g[10], nmn = g[11];
        const double loss_pre  = (npre > 0.0) ? spre / npre : spre;
        const double loss_next = (nnext > 0.0) ? snext / nnext : snext;
        const double loss      = (npre > 0.0 && nnext > 0.0) ? sall / npre : sall;
        const double loss_sim  = (nunion > 0.0) ? ssim / tnum : ssim;
        const double total = (loss_pre + loss_next + loss + loss_sim) * 0.25;
        const double ap = (nmp > 0.0) ? accp / nmp : accp + 1.0;
        const double an = (nmn > 0.0) ? accn / nmn : accn + 1.0;
        out[0] = (float)loss_pre;
        out[1] = (float)loss_next;
        out[2] = (float)loss_sim;
        out[3] = (float)total;
        out[4] = (float)ap;
        out[5] = (float)an;
        out[6] = (float)((ap + an) * 0.5);
    }
}

extern "C" void kernel_launch(void* const* d_in, const int* in_sizes, int n_in,
                              void* d_out, int out_size, void* d_ws, size_t ws_size,
                              hipStream_t stream) {
    const float* input  = (const float*)d_in[0];
    const int*   target = (const int*)d_in[1];
    const int*   mask0  = (const int*)d_in[2];
    const int*   mask1  = (const int*)d_in[3];
    float* out = (float*)d_out;
    float* part = (float*)d_ws;   // NACC * slices floats, AoS

    const int slices = in_sizes[0] / NEL;  // B*C = 2048

    const size_t need = (size_t)NACC * slices * sizeof(float) + sizeof(unsigned);
    unsigned* counter = nullptr;
    if (ws_size >= need)
        counter = (unsigned*)(part + (size_t)NACC * slices);  // no init needed (modulo winner)

    sst_main<<<slices, 512, 0, stream>>>(input, target, mask0, mask1, out, part, slices, counter);
    if (!counter)
        sst_final<<<1, 256, 0, stream>>>(part, slices, out);
}

// Round 4
// 159.456 us; speedup vs baseline: 1.3048x; 1.3048x over previous
//
#include <hip/hip_runtime.h>

#define M1 81
#define MSZ 80
#define NEL (M1 * M1)          // 6561
#define NTW ((NEL + 31) / 32)  // 206 words of target bits
#define NACC 12
#define BIGKC 1.0e30f

typedef __attribute__((address_space(1))) const void* gas_t;
typedef __attribute__((address_space(3))) void* las_t;

// accumulator indices:
// 0 target_num, 1 n_pre, 2 n_next, 3 n_union,
// 4 s_pre, 5 s_next, 6 s_all, 7 s_sim,
// 8 s_acc_pre, 9 s_acc_next, 10 n_mpre, 11 n_mnext

__global__ __launch_bounds__(512, 8) void sst_main(
    const float* __restrict__ input,
    const int* __restrict__ target,
    const int* __restrict__ mask0,
    const int* __restrict__ mask1,
    float* __restrict__ out_idx,   // d_out + 7, [slices*80] floats
    float* __restrict__ part,      // SoA: part[k*slices + slice]
    int slices)
{
    __shared__ __align__(16) float s_xraw[NEL + 4];  // x staged; e after sweep A
    __shared__ unsigned s_tb[NTW];      // target bits, row-major
    __shared__ float s_m0[M1], s_m1[M1];
    __shared__ float s_kc[M1];          // log(csum) (1e30 sentinel @80)
    __shared__ float s_invc[M1];        // 1/csum (0 sentinel @80 for argmax)
    __shared__ float s_pA[486];         // sweepA csum partials
    __shared__ float s_pC[480];         // sweepB rsum partials
    __shared__ float s_pV[486];         // argmax value partials (A: col, C: row)
    __shared__ unsigned char s_pI[486]; // argmax index partials
    __shared__ unsigned char s_pT[486]; // first-target partials (127 = none)
    __shared__ unsigned char s_ci[MSZ]; // per-column argmax row (from B-merge)
    __shared__ int s_ct[MSZ];           // per-column first target row (atomicMin)
    __shared__ unsigned s_m1w[4];       // m1 bitmask (bit c = mask1[c] != 0)
    __shared__ float s_wv[8][NACC];

    const int tid   = threadIdx.x;
    const int lane  = tid & 63;
    const int w     = tid >> 6;
    const int slice = blockIdx.x;
    const size_t base = (size_t)slice * NEL;

    // slice base (in floats) is ≡ slice (mod 4); shift LDS base so both the
    // global float4 pointer and the LDS destination are 16B aligned.
    float* sx = s_xraw + (slice & 3);
    const int h = (4 - (slice & 3)) & 3;      // scalar head elements

    if (tid < M1) s_m0[tid] = (float)mask0[slice * M1 + tid];
    else if (tid >= 128 && tid < 128 + M1) s_m1[tid - 128] = (float)mask1[slice * M1 + (tid - 128)];
    if (tid >= 256 && tid < 256 + MSZ) s_ct[tid - 256] = 0x7fffffff;

    float a[NACC];
#pragma unroll
    for (int k = 0; k < NACC; ++k) a[k] = 0.0f;

    // ---- staging: direct global->LDS DMA (lane pattern = base + lane*16,
    //      both sides 16B-aligned; full waves only on the DMA loads) ----
    if (tid < h) sx[tid] = input[base + tid];
    const float4* in4 = (const float4*)(input + base + h);
#pragma unroll
    for (int it = 0; it < 3; ++it) {          // 1536 float4s
        const int i = tid + (it << 9);
        __builtin_amdgcn_global_load_lds((gas_t)(in4 + i),
                                         (las_t)(sx + h + (i << 2)), 16, 0, 0);
    }
    {   // tail floats [h+6144, NEL): at most 417, one strided round
        const int i = h + 6144 + tid;
        if (i < NEL) sx[i] = input[base + i];
    }

    // target prefetch BEFORE B1: its latency merges into the same epoch B1
    // already waits on for the input staging (one drain covers both).
    int tpre[13];
#pragma unroll
    for (int k = 0; k < 13; ++k) {
        const int i = tid + (k << 9);
        tpre[k] = (i < NEL) ? target[base + i] : 0;
    }
    __syncthreads();   // B1 (drains DMA + scalar staging + target loads)

    // m1 bit windows (consumed in sweep C, after B3)
    if (w == 0) {
        const unsigned long long m = __ballot(s_m1[lane] != 0.0f);
        if (lane == 0) { s_m1w[0] = (unsigned)m; s_m1w[1] = (unsigned)(m >> 32); }
    } else if (w == 1) {
        float v = 0.0f;
        if (lane < 17) v = s_m1[64 + lane];
        const unsigned long long m = __ballot(v != 0.0f);
        if (lane == 0) { s_m1w[2] = (unsigned)m; s_m1w[3] = 0u; }
    }

    // ---- sweep A: columns (81 cols x 6 threads); store e = exp(m1c*m0r*x) ----
    if (tid < 486) {
        const int c = tid / 6, j = tid - 6 * (tid / 6);
        const int r0 = j * 13 + ((j < 3) ? j : 3);
        const int len = (j < 3) ? 14 : 13;
        const float m1c = s_m1[c];
        float cs = 0.0f, bv = -1.0f;
        int bi = r0;
        int idx = r0 * M1 + c;
        for (int i = 0; i < len; ++i, idx += M1) {
            const int r = r0 + i;
            const float z = m1c * s_m0[r] * sx[idx];
            const float e = __expf(z);
            sx[idx] = e;                      // same-thread overwrite: race-free
            cs += e;
            if (e > bv) { bv = e; bi = r; }   // first-max (ascending r)
        }
        s_pA[tid] = cs; s_pV[tid] = bv; s_pI[tid] = (unsigned char)bi;
    }

    // ---- target bit-pack (prefetched regs -> ballot -> s_tb) + target_num ----
#pragma unroll
    for (int k = 0; k < 13; ++k) {
        const int i = tid + (k << 9);
        if (i < NEL) {
            const unsigned long long m = __ballot(tpre[k] != 0);
            if (lane == 0) {
                a[0] += (float)__popcll(m);
                const int w2 = (i >> 5) & ~1;
                s_tb[w2] = (unsigned)m;
                if (w2 + 1 < NTW) s_tb[w2 + 1] = (unsigned)(m >> 32);
            }
        }
    }
    __syncthreads();   // B2

    // ---- sweep B (row e-sums, no exp) | column merge (tids 480..511) ----
    if (tid < 480) {
        const int r = tid / 6, j = tid - 6 * (tid / 6);
        const int c0 = j * 13 + ((j < 3) ? j : 3);
        const int len = (j < 3) ? 14 : 13;
        const int rb = r * M1 + c0;
        float rs = 0.0f;
        for (int i = 0; i < len; ++i) rs += sx[rb + i];
        s_pC[tid] = rs;
    } else {
        const int u = tid - 480;
        for (int c = u; c < M1; c += 32) {
            if (c < MSZ) {
                const int b = 6 * c;
                float cs = 0.0f;
#pragma unroll
                for (int k = 0; k < 6; ++k) cs += s_pA[b + k];
                float bv = s_pV[b]; int bi = s_pI[b];
#pragma unroll
                for (int k = 1; k < 6; ++k) {
                    const float v = s_pV[b + k];
                    if (v > bv) { bv = v; bi = s_pI[b + k]; }  // first-max
                }
                s_kc[c] = __logf(cs);
                s_invc[c] = 1.0f / cs;
                s_ci[c] = (unsigned char)bi;
            } else {
                s_kc[c] = BIGKC;     // col-80: pre-only in min(lr,kc)
                s_invc[c] = 0.0f;    // col-80: argmax uses e*invr only
            }
        }
    }
    __syncthreads();   // B3

    // ---- sweep C: rows 0..79 (tids 0..479) + row-80 next-terms (480..485) ----
    if (tid < 480) {
        const int r = tid / 6, j = tid - 6 * (tid / 6);
        const int c0 = j * 13 + ((j < 3) ? j : 3);
        const int len = (j < 3) ? 14 : 13;
        const int rb = r * M1;
        const int pb = 6 * r;
        const float rs = s_pC[pb] + s_pC[pb + 1] + s_pC[pb + 2]
                       + s_pC[pb + 3] + s_pC[pb + 4] + s_pC[pb + 5];
        const float lr = __logf(rs), invr = 1.0f / rs;
        const float m0f = s_m0[r];

        // bit window: t & m1 & m0 over cols [c0, c0+len)
        const int bp = rb + c0;
        const unsigned long long tw64 =
            ((unsigned long long)s_tb[(bp >> 5) + 1] << 32) | s_tb[bp >> 5];
        const int mp0 = c0 >> 5;
        const unsigned long long mw64 =
            ((unsigned long long)s_m1w[mp0 + 1] << 32) | s_m1w[mp0];
        const unsigned lenmask = (1u << len) - 1u;
        unsigned wb = (unsigned)(tw64 >> (bp & 31)) & (unsigned)(mw64 >> (c0 & 31)) & lenmask;
        if (m0f == 0.0f) wb = 0u;

        const unsigned w3 = (j == 5) ? (wb & 0x0FFFu) : wb;  // drop c=80 bit
        a[1] += (float)__popc(wb);   // n_pre
        a[2] += (float)__popc(w3);   // n_next (rows<80 part)
        a[3] += (float)__popc(w3);   // n_union
        const int ti = wb ? (c0 + __ffs(wb) - 1) : 127;

        // row argmax of input_all = e * max(invr, invc)  (linear domain,
        // structurally identical to reference max(input_pre, input_next))
        float bv = -1.0f; int bi = c0;
        for (int i = 0; i < len; ++i) {
            const int c = c0 + i;
            const float val = sx[rb + c] * fmaxf(invr, s_invc[c]);
            if (val > bv) { bv = val; bi = c; }   // strict >, ascending: first-max
        }
        // sparse t-terms (z recovered by logf; ~1.7 bits/thread avg)
        unsigned wl = wb;
        while (wl) {
            const int b = __ffs(wl) - 1; wl &= wl - 1u;
            const int c = c0 + b;
            const float e = sx[rb + c];
            const float z = __logf(e);
            a[4] += lr - z;                              // s_pre
            a[6] += fminf(lr, s_kc[c]) - z;              // s_all (c=80: min=lr)
            if (c != MSZ) {
                a[5] += s_kc[c] - z;                     // s_next (rows<80 part)
                a[7] = fmaf(e, fabsf(s_invc[c] - invr), a[7]);  // sim (union)
                atomicMin(&s_ct[c], r);                  // first target row / col
            }
        }
        s_pV[tid] = bv; s_pI[tid] = (unsigned char)bi; s_pT[tid] = (unsigned char)ti;
    } else if (tid < 486) {
        // row 80: only n_next / s_next / ct terms survive
        const int j = tid - 480;
        const int c0 = j * 13 + ((j < 3) ? j : 3);
        const int len = (j < 3) ? 14 : 13;
        const int rb = MSZ * M1;
        const float m80 = s_m0[MSZ];
        const int bp = rb + c0;
        const unsigned long long tw64 =
            ((unsigned long long)s_tb[(bp >> 5) + 1] << 32) | s_tb[bp >> 5];
        const int mp0 = c0 >> 5;
        const unsigned long long mw64 =
            ((unsigned long long)s_m1w[mp0 + 1] << 32) | s_m1w[mp0];
        const unsigned lenmask = (1u << len) - 1u;
        unsigned wb = (unsigned)(tw64 >> (bp & 31)) & (unsigned)(mw64 >> (c0 & 31)) & lenmask;
        if (m80 == 0.0f) wb = 0u;
        if (j == 5) wb &= 0x0FFFu;                       // next-mask zeroes col 80
        a[2] += (float)__popc(wb);
        while (wb) {
            const int b = __ffs(wb) - 1; wb &= wb - 1u;
            const int c = c0 + b;
            a[5] += s_kc[c] - __logf(sx[rb + c]);
            atomicMin(&s_ct[c], MSZ);
        }
    }
    __syncthreads();   // B4

    if (tid < MSZ) {   // merge row argmax + accuracy_pre
        const int b = 6 * tid;
        float bv = s_pV[b]; int bi = s_pI[b];
#pragma unroll
        for (int k = 1; k < 6; ++k) {
            const float v = s_pV[b + k];
            if (v > bv) { bv = v; bi = s_pI[b + k]; }
        }
        int ti = 127;
#pragma unroll
        for (int k = 0; k < 6; ++k) ti = min(ti, (int)s_pT[b + k]);
        if (ti == 127) ti = 0;
        out_idx[(size_t)slice * MSZ + tid] = (float)bi;
        const float m0f = s_m0[tid];
        a[8]  += (bi == ti) ? m0f : 0.0f;
        a[10] += m0f;
    } else if (tid >= 128 && tid < 128 + MSZ) {   // accuracy_next (cols 0..79)
        const int c = tid - 128;
        const int ctv = s_ct[c];
        const int ti = (ctv == 0x7fffffff) ? 0 : ctv;
        const int bi = (int)s_ci[c];
        const float m1c = s_m1[c];
        a[9]  += (bi == ti) ? m1c : 0.0f;
        a[11] += m1c;
    }

    // ---- block reduce: wave shuffle -> LDS -> SoA partials ----
#pragma unroll
    for (int k = 0; k < NACC; ++k) {
        float v = a[k];
        for (int off = 32; off > 0; off >>= 1) v += __shfl_down(v, off);
        if (lane == 0) s_wv[w][k] = v;
    }
    __syncthreads();   // B5
    if (tid < NACC) {
        float s = 0.0f;
#pragma unroll
        for (int ww = 0; ww < 8; ++ww) s += s_wv[ww][tid];
        part[(size_t)tid * slices + slice] = s;
    }
}

__global__ __launch_bounds__(256) void sst_final(
    const float* __restrict__ part, int slices, float* __restrict__ out)
{
    __shared__ double s_part[4][NACC];
    const int tid = threadIdx.x;
    double l[NACC];
#pragma unroll
    for (int k = 0; k < NACC; ++k) l[k] = 0.0;
    for (int s = tid; s < slices; s += 256) {
#pragma unroll
        for (int k = 0; k < NACC; ++k) l[k] += (double)part[(size_t)k * slices + s];
    }
#pragma unroll
    for (int k = 0; k < NACC; ++k) {
        double v = l[k];
        for (int off = 32; off > 0; off >>= 1) v += __shfl_down(v, off);
        if ((tid & 63) == 0) s_part[tid >> 6][k] = v;
    }
    __syncthreads();
    if (tid == 0) {
        double g[NACC];
#pragma unroll
        for (int k = 0; k < NACC; ++k)
            g[k] = s_part[0][k] + s_part[1][k] + s_part[2][k] + s_part[3][k];
        const double tnum = g[0], npre = g[1], nnext = g[2], nunion = g[3];
        const double spre = g[4], snext = g[5], sall = g[6], ssim = g[7];
        const double accp = g[8], accn = g[9], nmp = g[10], nmn = g[11];
        const double loss_pre  = (npre > 0.0) ? spre / npre : spre;
        const double loss_next = (nnext > 0.0) ? snext / nnext : snext;
        const double loss      = (npre > 0.0 && nnext > 0.0) ? sall / npre : sall;
        const double loss_sim  = (nunion > 0.0) ? ssim / tnum : ssim;
        const double total = (loss_pre + loss_next + loss + loss_sim) * 0.25;
        const double ap = (nmp > 0.0) ? accp / nmp : accp + 1.0;
        const double an = (nmn > 0.0) ? accn / nmn : accn + 1.0;
        out[0] = (float)loss_pre;
        out[1] = (float)loss_next;
        out[2] = (float)loss_sim;
        out[3] = (float)total;
        out[4] = (float)ap;
        out[5] = (float)an;
        out[6] = (float)((ap + an) * 0.5);
    }
}

extern "C" void kernel_launch(void* const* d_in, const int* in_sizes, int n_in,
                              void* d_out, int out_size, void* d_ws, size_t ws_size,
                              hipStream_t stream) {
    const float* input  = (const float*)d_in[0];
    const int*   target = (const int*)d_in[1];
    const int*   mask0  = (const int*)d_in[2];
    const int*   mask1  = (const int*)d_in[3];
    float* out = (float*)d_out;
    float* part = (float*)d_ws;   // NACC * slices floats, SoA

    const int slices = in_sizes[0] / NEL;  // B*C = 2048

    sst_main<<<slices, 512, 0, stream>>>(input, target, mask0, mask1, out + 7, part, slices);
    sst_final<<<1, 256, 0, stream>>>(part, slices, out);
}

// Round 5
// 155.582 us; speedup vs baseline: 1.3373x; 1.0249x over previous
//
#include <hip/hip_runtime.h>

#define M1 81
#define MSZ 80
#define NEL (M1 * M1)          // 6561
#define NTW ((NEL + 31) / 32)  // 206 words of target bits
#define NACC 12
#define BIGKC 1.0e30f

// accumulator indices:
// 0 target_num, 1 n_pre, 2 n_next, 3 n_union,
// 4 s_pre, 5 s_next, 6 s_all, 7 s_sim,
// 8 s_acc_pre, 9 s_acc_next, 10 n_mpre, 11 n_mnext

__global__ __launch_bounds__(512, 8) void sst_main(
    const float* __restrict__ input,
    const int* __restrict__ target,
    const int* __restrict__ mask0,
    const int* __restrict__ mask1,
    float* __restrict__ out_idx,   // d_out + 7, [slices*80] floats
    float* __restrict__ part,      // SoA: part[k*slices + slice]
    int slices)
{
    __shared__ __align__(16) float s_x[NEL];   // e-values (written by sweep A)
    __shared__ unsigned s_tb[NTW];      // target bits, row-major
    __shared__ float s_m0[M1], s_m1[M1];
    __shared__ float s_kc[M1];          // log(csum) (1e30 sentinel @80)
    __shared__ float s_invc[M1];        // 1/csum (0 sentinel @80 for argmax)
    __shared__ float s_pA[486];         // sweepA csum partials
    __shared__ float s_pC[480];         // sweepB rsum partials
    __shared__ float s_pV[486];         // argmax value partials (A: col, C: row)
    __shared__ unsigned char s_pI[486]; // argmax index partials
    __shared__ unsigned char s_pT[486]; // first-target partials (127 = none)
    __shared__ unsigned char s_ci[MSZ]; // per-column argmax row (from B-merge)
    __shared__ int s_ct[MSZ];           // per-column first target row (atomicMin)
    __shared__ unsigned s_m1w[4];       // m1 bitmask (bit c = mask1[c] != 0)
    __shared__ float s_wv[8][NACC];

    const int tid   = threadIdx.x;
    const int lane  = tid & 63;
    const int w     = tid >> 6;
    const int slice = blockIdx.x;
    const size_t base = (size_t)slice * NEL;

    if (tid < M1) s_m0[tid] = (float)mask0[slice * M1 + tid];
    else if (tid >= 128 && tid < 128 + M1) s_m1[tid - 128] = (float)mask1[slice * M1 + (tid - 128)];
    if (tid >= 256 && tid < 256 + MSZ) s_ct[tid - 256] = 0x7fffffff;

    float a[NACC];
#pragma unroll
    for (int k = 0; k < NACC; ++k) a[k] = 0.0f;

    __syncthreads();   // B1 (masks + s_ct only — no bulk staging to drain)

    // ---- sweep A issue: stream x column-strided from global into regs.
    //      13-14 independent loads/thread, issued FIRST so A's compute waits
    //      only on these (FIFO vmcnt); target prefetch issued after stays in
    //      flight through the whole exp phase.
    const bool actA = (tid < 486);
    const int cA = tid / 6, jA = tid - 6 * (tid / 6);
    const int r0 = jA * 13 + ((jA < 3) ? jA : 3);
    const bool has14 = (jA < 3);
    float v[14];
    if (actA) {
        const float* gp = input + base + (size_t)r0 * M1 + cA;
#pragma unroll
        for (int i = 0; i < 13; ++i) v[i] = gp[i * M1];
        // 14th load: clamped address for j==5 (r0+13 == 81 would leave the
        // slice); value only consumed when has14 (j<3), where it's in-bounds.
        v[13] = gp[((jA < 5) ? 13 : 0) * M1];
    }

    // target prefetch: consumed at the bit-pack AFTER sweep A -> latency
    // hides under the exp compute.
    int tpre[13];
#pragma unroll
    for (int k = 0; k < 13; ++k) {
        const int i = tid + (k << 9);
        tpre[k] = (i < NEL) ? target[base + i] : 0;
    }

    // m1 bit windows (consumed in sweep C, after B3)
    if (w == 0) {
        const unsigned long long m = __ballot(s_m1[lane] != 0.0f);
        if (lane == 0) { s_m1w[0] = (unsigned)m; s_m1w[1] = (unsigned)(m >> 32); }
    } else if (w == 1) {
        float vv = 0.0f;
        if (lane < 17) vv = s_m1[64 + lane];
        const unsigned long long m = __ballot(vv != 0.0f);
        if (lane == 0) { s_m1w[2] = (unsigned)m; s_m1w[3] = 0u; }
    }

    // ---- sweep A compute: columns (81 cols x 6 threads); store e to LDS ----
    if (actA) {
        const float m1c = s_m1[cA];
        float cs = 0.0f, bv = -1.0f;
        int bi = r0;
        int idx = r0 * M1 + cA;
#pragma unroll
        for (int i = 0; i < 13; ++i, idx += M1) {
            const int r = r0 + i;
            const float z = m1c * s_m0[r] * v[i];
            const float e = __expf(z);
            s_x[idx] = e;                     // same-thread region: race-free
            cs += e;
            if (e > bv) { bv = e; bi = r; }   // first-max (ascending r)
        }
        if (has14) {
            const int r = r0 + 13;
            const float z = m1c * s_m0[r] * v[13];
            const float e = __expf(z);
            s_x[idx] = e;
            cs += e;
            if (e > bv) { bv = e; bi = r; }
        }
        s_pA[tid] = cs; s_pV[tid] = bv; s_pI[tid] = (unsigned char)bi;
    }

    // ---- target bit-pack (prefetched regs -> ballot -> s_tb) + target_num ----
#pragma unroll
    for (int k = 0; k < 13; ++k) {
        const int i = tid + (k << 9);
        if (i < NEL) {
            const unsigned long long m = __ballot(tpre[k] != 0);
            if (lane == 0) {
                a[0] += (float)__popcll(m);
                const int w2 = (i >> 5) & ~1;
                s_tb[w2] = (unsigned)m;
                if (w2 + 1 < NTW) s_tb[w2 + 1] = (unsigned)(m >> 32);
            }
        }
    }
    __syncthreads();   // B2

    // ---- sweep B (row e-sums, no exp) | column merge (tids 480..511) ----
    if (tid < 480) {
        const int r = tid / 6, j = tid - 6 * (tid / 6);
        const int c0 = j * 13 + ((j < 3) ? j : 3);
        const int len = (j < 3) ? 14 : 13;
        const int rb = r * M1 + c0;
        float rs = 0.0f;
        for (int i = 0; i < len; ++i) rs += s_x[rb + i];
        s_pC[tid] = rs;
    } else {
        const int u = tid - 480;
        for (int c = u; c < M1; c += 32) {
            if (c < MSZ) {
                const int b = 6 * c;
                float cs = 0.0f;
#pragma unroll
                for (int k = 0; k < 6; ++k) cs += s_pA[b + k];
                float bv = s_pV[b]; int bi = s_pI[b];
#pragma unroll
                for (int k = 1; k < 6; ++k) {
                    const float vv = s_pV[b + k];
                    if (vv > bv) { bv = vv; bi = s_pI[b + k]; }  // first-max
                }
                s_kc[c] = __logf(cs);
                s_invc[c] = 1.0f / cs;
                s_ci[c] = (unsigned char)bi;
            } else {
                s_kc[c] = BIGKC;     // col-80: pre-only in min(lr,kc)
                s_invc[c] = 0.0f;    // col-80: argmax uses e*invr only
            }
        }
    }
    __syncthreads();   // B3

    // ---- sweep C: rows 0..79 (tids 0..479) + row-80 next-terms (480..485) ----
    if (tid < 480) {
        const int r = tid / 6, j = tid - 6 * (tid / 6);
        const int c0 = j * 13 + ((j < 3) ? j : 3);
        const int len = (j < 3) ? 14 : 13;
        const int rb = r * M1;
        const int pb = 6 * r;
        const float rs = s_pC[pb] + s_pC[pb + 1] + s_pC[pb + 2]
                       + s_pC[pb + 3] + s_pC[pb + 4] + s_pC[pb + 5];
        const float lr = __logf(rs), invr = 1.0f / rs;
        const float m0f = s_m0[r];

        // bit window: t & m1 & m0 over cols [c0, c0+len)
        const int bp = rb + c0;
        const unsigned long long tw64 =
            ((unsigned long long)s_tb[(bp >> 5) + 1] << 32) | s_tb[bp >> 5];
        const int mp0 = c0 >> 5;
        const unsigned long long mw64 =
            ((unsigned long long)s_m1w[mp0 + 1] << 32) | s_m1w[mp0];
        const unsigned lenmask = (1u << len) - 1u;
        unsigned wb = (unsigned)(tw64 >> (bp & 31)) & (unsigned)(mw64 >> (c0 & 31)) & lenmask;
        if (m0f == 0.0f) wb = 0u;

        const unsigned w3 = (j == 5) ? (wb & 0x0FFFu) : wb;  // drop c=80 bit
        a[1] += (float)__popc(wb);   // n_pre
        a[2] += (float)__popc(w3);   // n_next (rows<80 part)
        a[3] += (float)__popc(w3);   // n_union
        const int ti = wb ? (c0 + __ffs(wb) - 1) : 127;

        // row argmax of input_all = e * max(invr, invc)  (linear domain,
        // structurally identical to reference max(input_pre, input_next))
        float bv = -1.0f; int bi = c0;
        for (int i = 0; i < len; ++i) {
            const int c = c0 + i;
            const float val = s_x[rb + c] * fmaxf(invr, s_invc[c]);
            if (val > bv) { bv = val; bi = c; }   // strict >, ascending: first-max
        }
        // sparse t-terms (z recovered by logf; ~1.7 bits/thread avg)
        unsigned wl = wb;
        while (wl) {
            const int b = __ffs(wl) - 1; wl &= wl - 1u;
            const int c = c0 + b;
            const float e = s_x[rb + c];
            const float z = __logf(e);
            a[4] += lr - z;                              // s_pre
            a[6] += fminf(lr, s_kc[c]) - z;              // s_all (c=80: min=lr)
            if (c != MSZ) {
                a[5] += s_kc[c] - z;                     // s_next (rows<80 part)
                a[7] = fmaf(e, fabsf(s_invc[c] - invr), a[7]);  // sim (union)
                atomicMin(&s_ct[c], r);                  // first target row / col
            }
        }
        s_pV[tid] = bv; s_pI[tid] = (unsigned char)bi; s_pT[tid] = (unsigned char)ti;
    } else if (tid < 486) {
        // row 80: only n_next / s_next / ct terms survive
        const int j = tid - 480;
        const int c0 = j * 13 + ((j < 3) ? j : 3);
        const int len = (j < 3) ? 14 : 13;
        const int rb = MSZ * M1;
        const float m80 = s_m0[MSZ];
        const int bp = rb + c0;
        const unsigned long long tw64 =
            ((unsigned long long)s_tb[(bp >> 5) + 1] << 32) | s_tb[bp >> 5];
        const int mp0 = c0 >> 5;
        const unsigned long long mw64 =
            ((unsigned long long)s_m1w[mp0 + 1] << 32) | s_m1w[mp0];
        const unsigned lenmask = (1u << len) - 1u;
        unsigned wb = (unsigned)(tw64 >> (bp & 31)) & (unsigned)(mw64 >> (c0 & 31)) & lenmask;
        if (m80 == 0.0f) wb = 0u;
        if (j == 5) wb &= 0x0FFFu;                       // next-mask zeroes col 80
        a[2] += (float)__popc(wb);
        while (wb) {
            const int b = __ffs(wb) - 1; wb &= wb - 1u;
            const int c = c0 + b;
            a[5] += s_kc[c] - __logf(s_x[rb + c]);
            atomicMin(&s_ct[c], MSZ);
        }
    }
    __syncthreads();   // B4

    if (tid < MSZ) {   // merge row argmax + accuracy_pre
        const int b = 6 * tid;
        float bv = s_pV[b]; int bi = s_pI[b];
#pragma unroll
        for (int k = 1; k < 6; ++k) {
            const float vv = s_pV[b + k];
            if (vv > bv) { bv = vv; bi = s_pI[b + k]; }
        }
        int ti = 127;
#pragma unroll
        for (int k = 0; k < 6; ++k) ti = min(ti, (int)s_pT[b + k]);
        if (ti == 127) ti = 0;
        out_idx[(size_t)slice * MSZ + tid] = (float)bi;
        const float m0f = s_m0[tid];
        a[8]  += (bi == ti) ? m0f : 0.0f;
        a[10] += m0f;
    } else if (tid >= 128 && tid < 128 + MSZ) {   // accuracy_next (cols 0..79)
        const int c = tid - 128;
        const int ctv = s_ct[c];
        const int ti = (ctv == 0x7fffffff) ? 0 : ctv;
        const int bi = (int)s_ci[c];
        const float m1c = s_m1[c];
        a[9]  += (bi == ti) ? m1c : 0.0f;
        a[11] += m1c;
    }

    // ---- block reduce: wave shuffle -> LDS -> SoA partials ----
#pragma unroll
    for (int k = 0; k < NACC; ++k) {
        float vv = a[k];
        for (int off = 32; off > 0; off >>= 1) vv += __shfl_down(vv, off);
        if (lane == 0) s_wv[w][k] = vv;
    }
    __syncthreads();   // B5
    if (tid < NACC) {
        float s = 0.0f;
#pragma unroll
        for (int ww = 0; ww < 8; ++ww) s += s_wv[ww][tid];
        part[(size_t)tid * slices + slice] = s;
    }
}

__global__ __launch_bounds__(256) void sst_final(
    const float* __restrict__ part, int slices, float* __restrict__ out)
{
    __shared__ double s_part[4][NACC];
    const int tid = threadIdx.x;
    double l[NACC];
#pragma unroll
    for (int k = 0; k < NACC; ++k) l[k] = 0.0;
    for (int s = tid; s < slices; s += 256) {
#pragma unroll
        for (int k = 0; k < NACC; ++k) l[k] += (double)part[(size_t)k * slices + s];
    }
#pragma unroll
    for (int k = 0; k < NACC; ++k) {
        double v = l[k];
        for (int off = 32; off > 0; off >>= 1) v += __shfl_down(v, off);
        if ((tid & 63) == 0) s_part[tid >> 6][k] = v;
    }
    __syncthreads();
    if (tid == 0) {
        double g[NACC];
#pragma unroll
        for (int k = 0; k < NACC; ++k)
            g[k] = s_part[0][k] + s_part[1][k] + s_part[2][k] + s_part[3][k];
        const double tnum = g[0], npre = g[1], nnext = g[2], nunion = g[3];
        const double spre = g[4], snext = g[5], sall = g[6], ssim = g[7];
        const double accp = g[8], accn = g[9], nmp = g[10], nmn = g[11];
        const double loss_pre  = (npre > 0.0) ? spre / npre : spre;
        const double loss_next = (nnext > 0.0) ? snext / nnext : snext;
        const double loss      = (npre > 0.0 && nnext > 0.0) ? sall / npre : sall;
        const double loss_sim  = (nunion > 0.0) ? ssim / tnum : ssim;
        const double total = (loss_pre + loss_next + loss + loss_sim) * 0.25;
        const double ap = (nmp > 0.0) ? accp / nmp : accp + 1.0;
        const double an = (nmn > 0.0) ? accn / nmn : accn + 1.0;
        out[0] = (float)loss_pre;
        out[1] = (float)loss_next;
        out[2] = (float)loss_sim;
        out[3] = (float)total;
        out[4] = (float)ap;
        out[5] = (float)an;
        out[6] = (float)((ap + an) * 0.5);
    }
}

extern "C" void kernel_launch(void* const* d_in, const int* in_sizes, int n_in,
                              void* d_out, int out_size, void* d_ws, size_t ws_size,
                              hipStream_t stream) {
    const float* input  = (const float*)d_in[0];
    const int*   target = (const int*)d_in[1];
    const int*   mask0  = (const int*)d_in[2];
    const int*   mask1  = (const int*)d_in[3];
    float* out = (float*)d_out;
    float* part = (float*)d_ws;   // NACC * slices floats, SoA

    const int slices = in_sizes[0] / NEL;  // B*C = 2048

    sst_main<<<slices, 512, 0, stream>>>(input, target, mask0, mask1, out + 7, part, slices);
    sst_final<<<1, 256, 0, stream>>>(part, slices, out);
}

// Round 6
// 151.661 us; speedup vs baseline: 1.3719x; 1.0259x over previous
//
#include <hip/hip_runtime.h>

#define M1 81
#define MSZ 80
#define NEL (M1 * M1)          // 6561
#define NTW ((NEL + 31) / 32)  // 206 words of target bits
#define NACC 12
#define BIGKC 1.0e30f
#define REDP 517               // padded stride for reduce scratch (bank spread)

// accumulator indices:
// 0 target_num, 1 n_pre, 2 n_next, 3 n_union,
// 4 s_pre, 5 s_next, 6 s_all, 7 s_sim,
// 8 s_acc_pre, 9 s_acc_next, 10 n_mpre, 11 n_mnext

__global__ __launch_bounds__(512, 8) void sst_main(
    const float* __restrict__ input,
    const int* __restrict__ target,
    const int* __restrict__ mask0,
    const int* __restrict__ mask1,
    float* __restrict__ out_idx,   // d_out + 7, [slices*80] floats
    float* __restrict__ part,      // SoA: part[k*slices + slice]
    int slices)
{
    __shared__ __align__(16) float s_x[NEL];  // e-values; reduce scratch at end
    __shared__ unsigned s_tb[NTW];      // target bits, row-major
    __shared__ float s_m0[M1], s_m1[M1];
    __shared__ float s_kc[M1];          // log(csum) (1e30 sentinel @80)
    __shared__ float s_invc[M1];        // 1/csum (0 sentinel @80 for argmax)
    __shared__ unsigned char s_ci[M1];  // per-column argmax row
    __shared__ int s_ct[MSZ];           // per-column first target row (atomicMin)
    __shared__ unsigned s_m1w[4];       // m1 bitmask (bit c = mask1[c] != 0)

    const int tid   = threadIdx.x;
    const int lane  = tid & 63;
    const int slice = blockIdx.x;
    const size_t base = (size_t)slice * NEL;

    // 4-thread groups (lane-aligned): group g = tid>>2 is a column in sweep A,
    // a row in sweep C; j4 = tid&3 selects the 21/20/20/20 line split.
    const bool act = (tid < 4 * M1);          // 324 threads
    const int g   = tid >> 2;
    const int j4  = tid & 3;
    const int c0j = (j4 == 0) ? 0 : (1 + 20 * j4);   // {0,21,41,61}
    const int lm1 = (j4 == 0) ? 0x1FFFFF : 0xFFFFF;  // 21- / 20-bit masks

    if (tid < M1) s_m0[tid] = (float)mask0[slice * M1 + tid];
    else if (tid >= 128 && tid < 128 + M1) s_m1[tid - 128] = (float)mask1[slice * M1 + (tid - 128)];
    if (tid >= 256 && tid < 256 + MSZ) s_ct[tid - 256] = 0x7fffffff;

    float a[NACC];
#pragma unroll
    for (int k = 0; k < NACC; ++k) a[k] = 0.0f;

    __syncthreads();   // B1 (masks + s_ct)

    // ---- sweep A issue: column-strided loads into regs (issued first, so
    //      A's compute waits only on these; FIFO vmcnt) ----
    float v[21];
    if (act) {
        const float* gp = input + base + (size_t)c0j * M1 + g;
#pragma unroll
        for (int i = 0; i < 20; ++i) v[i] = gp[i * M1];
        // 21st element only for j4==0 (rows 0..20); clamp addr for others
        v[20] = gp[((j4 == 0) ? 20 : 0) * M1];
    }

    // target prefetch: consumed after sweep A -> latency hides under exp
    int tpre[13];
#pragma unroll
    for (int k = 0; k < 13; ++k) {
        const int i = tid + (k << 9);
        tpre[k] = (i < NEL) ? target[base + i] : 0;
    }

    // m1 bit windows (consumed in sweep C)
    if ((tid >> 6) == 0) {
        const unsigned long long m = __ballot(s_m1[lane] != 0.0f);
        if (lane == 0) { s_m1w[0] = (unsigned)m; s_m1w[1] = (unsigned)(m >> 32); }
    } else if ((tid >> 6) == 1) {
        float vv = 0.0f;
        if (lane < 17) vv = s_m1[64 + lane];
        const unsigned long long m = __ballot(vv != 0.0f);
        if (lane == 0) { s_m1w[2] = (unsigned)m; s_m1w[3] = 0u; }
    }

    // ---- sweep A compute: 4 threads per column; butterfly merges the
    //      column sum + first-max argmax in-register (no LDS partials) ----
    if (act) {
        const int c = g;
        const float m1c = s_m1[c];
        float cs = 0.0f, bv = -1.0f;
        int bi = c0j;
        int idx = c0j * M1 + c;
#pragma unroll
        for (int i = 0; i < 20; ++i, idx += M1) {
            const int r = c0j + i;
            const float z = m1c * s_m0[r] * v[i];
            const float e = __expf(z);
            s_x[idx] = e;                     // same-thread region: race-free
            cs += e;
            if (e > bv) { bv = e; bi = r; }   // first-max (ascending r)
        }
        if (j4 == 0) {                        // row 20 (scanned last: ascending)
            const float z = m1c * s_m0[20] * v[20];
            const float e = __expf(z);
            s_x[20 * M1 + c] = e;
            cs += e;
            if (e > bv) { bv = e; bi = 20; }
        }
        // butterfly over the aligned 4-lane group; left-preferring tournament
        // reproduces first-max over ascending r exactly.
#pragma unroll
        for (int m = 1; m <= 2; m <<= 1) {
            const float pcs = __shfl_xor(cs, m);
            const float pbv = __shfl_xor(bv, m);
            const int   pbi = __shfl_xor(bi, m);
            cs += pcs;
            const bool take = (lane & m) ? (pbv >= bv) : (pbv > bv);
            if (take) { bv = pbv; bi = pbi; }
        }
        if (j4 == 0) {
            s_kc[c]   = (c == MSZ) ? BIGKC : __logf(cs);
            s_invc[c] = (c == MSZ) ? 0.0f  : 1.0f / cs;
            s_ci[c]   = (unsigned char)bi;
        }
    }

    // ---- target bit-pack (prefetched regs -> ballot -> s_tb) + target_num ----
#pragma unroll
    for (int k = 0; k < 13; ++k) {
        const int i = tid + (k << 9);
        if (i < NEL) {
            const unsigned long long m = __ballot(tpre[k] != 0);
            if (lane == 0) {
                a[0] += (float)__popcll(m);
                const int w2 = (i >> 5) & ~1;
                s_tb[w2] = (unsigned)m;
                if (w2 + 1 < NTW) s_tb[w2 + 1] = (unsigned)(m >> 32);
            }
        }
    }
    __syncthreads();   // B2

    // ---- sweep C: 4 threads per row; row sum + argmax + sparse terms,
    //      merged in-register via butterfly (sweep B deleted) ----
    if (act) {
        const int r = g;
        const int rb = r * M1;
        // bit window: t & m1 over cols [c0j, c0j+len)
        const int bp = rb + c0j;
        const unsigned long long tw64 =
            ((unsigned long long)s_tb[(bp >> 5) + 1] << 32) | s_tb[bp >> 5];
        const int mp0 = c0j >> 5;
        const unsigned long long mw64 =
            ((unsigned long long)s_m1w[mp0 + 1] << 32) | s_m1w[mp0];
        unsigned wb = (unsigned)(tw64 >> (bp & 31)) & (unsigned)(mw64 >> (c0j & 31)) & (unsigned)lm1;

        if (r < MSZ) {
            const float m0f = s_m0[r];
            if (m0f == 0.0f) wb = 0u;
            // row sum (own line, then 2-stage butterfly -> all 4 lanes)
            float rs = 0.0f;
#pragma unroll
            for (int i = 0; i < 20; ++i) rs += s_x[rb + c0j + i];
            if (j4 == 0) rs += s_x[rb + 20];
            rs += __shfl_xor(rs, 1);
            rs += __shfl_xor(rs, 2);
            const float lr = __logf(rs), invr = 1.0f / rs;

            const unsigned w3 = (j4 == 3) ? (wb & 0x7FFFFu) : wb;  // drop c=80
            a[1] += (float)__popc(wb);   // n_pre
            a[2] += (float)__popc(w3);   // n_next (rows<80 part)
            a[3] += (float)__popc(w3);   // n_union
            int ti = wb ? (c0j + __ffs(wb) - 1) : 127;

            // row argmax of input_all = e * max(invr, invc)
            float bv = -1.0f; int bi = c0j;
#pragma unroll
            for (int i = 0; i < 20; ++i) {
                const int c = c0j + i;
                const float val = s_x[rb + c] * fmaxf(invr, s_invc[c]);
                if (val > bv) { bv = val; bi = c; }   // strict >: first-max
            }
            if (j4 == 0) {
                const float val = s_x[rb + 20] * fmaxf(invr, s_invc[20]);
                if (val > bv) { bv = val; bi = 20; }
            }
            // sparse t-terms
            unsigned wl = wb;
            while (wl) {
                const int b = __ffs(wl) - 1; wl &= wl - 1u;
                const int c = c0j + b;
                const float e = s_x[rb + c];
                const float z = __logf(e);
                a[4] += lr - z;                              // s_pre
                a[6] += fminf(lr, s_kc[c]) - z;              // s_all (c=80: min=lr)
                if (c != MSZ) {
                    a[5] += s_kc[c] - z;                     // s_next (rows<80)
                    a[7] = fmaf(e, fabsf(s_invc[c] - invr), a[7]);  // sim
                    atomicMin(&s_ct[c], r);                  // first target row
                }
            }
            // butterfly merge: argmax (left-pref) + first-target (min)
#pragma unroll
            for (int m = 1; m <= 2; m <<= 1) {
                const float pbv = __shfl_xor(bv, m);
                const int   pbi = __shfl_xor(bi, m);
                const int   pti = __shfl_xor(ti, m);
                const bool take = (lane & m) ? (pbv >= bv) : (pbv > bv);
                if (take) { bv = pbv; bi = pbi; }
                ti = min(ti, pti);
            }
            if (j4 == 0) {
                if (ti == 127) ti = 0;
                out_idx[(size_t)slice * MSZ + r] = (float)bi;
                a[8]  += (bi == ti) ? m0f : 0.0f;
                a[10] += m0f;
            }
        } else {
            // row 80: only n_next / s_next / ct terms survive
            if (s_m0[MSZ] == 0.0f) wb = 0u;
            if (j4 == 3) wb &= 0x7FFFFu;                     // drop c=80
            a[2] += (float)__popc(wb);
            while (wb) {
                const int b = __ffs(wb) - 1; wb &= wb - 1u;
                const int c = c0j + b;
                a[5] += s_kc[c] - __logf(s_x[rb + c]);
                atomicMin(&s_ct[c], MSZ);
            }
        }
    }
    __syncthreads();   // B4 (s_ct/argmax done; s_x reads done)

    if (tid < MSZ) {   // accuracy_next (cols 0..79)
        const int ctv = s_ct[tid];
        const int ti = (ctv == 0x7fffffff) ? 0 : ctv;
        const int bi = (int)s_ci[tid];
        const float m1c = s_m1[tid];
        a[9]  += (bi == ti) ? m1c : 0.0f;
        a[11] += m1c;
    }

    // ---- block reduce: LDS transpose (s_x is dead -> scratch) ----
    // writers: 12 conflict-free ds_write per thread (consecutive tids).
    float* red = s_x;
#pragma unroll
    for (int k = 0; k < NACC; ++k) red[k * REDP + tid] = a[k];
    __syncthreads();   // B5
    if (tid < 96) {
        const int k = tid >> 3, u = tid & 7;
        const int b0 = k * REDP + u * 64;
        const int i0 = u * 4;                 // bank stagger across u
        float s = 0.0f;
        for (int i = 0; i < 64; ++i) s += red[b0 + ((i0 + i) & 63)];
        s += __shfl_xor(s, 1);
        s += __shfl_xor(s, 2);
        s += __shfl_xor(s, 4);
        if (u == 0) part[(size_t)k * slices + slice] = s;
    }
}

__global__ __launch_bounds__(256) void sst_final(
    const float* __restrict__ part, int slices, float* __restrict__ out)
{
    __shared__ double s_part[4][NACC];
    const int tid = threadIdx.x;
    double l[NACC];
#pragma unroll
    for (int k = 0; k < NACC; ++k) l[k] = 0.0;
    for (int s = tid; s < slices; s += 256) {
#pragma unroll
        for (int k = 0; k < NACC; ++k) l[k] += (double)part[(size_t)k * slices + s];
    }
#pragma unroll
    for (int k = 0; k < NACC; ++k) {
        double v = l[k];
        for (int off = 32; off > 0; off >>= 1) v += __shfl_down(v, off);
        if ((tid & 63) == 0) s_part[tid >> 6][k] = v;
    }
    __syncthreads();
    if (tid == 0) {
        double g[NACC];
#pragma unroll
        for (int k = 0; k < NACC; ++k)
            g[k] = s_part[0][k] + s_part[1][k] + s_part[2][k] + s_part[3][k];
        const double tnum = g[0], npre = g[1], nnext = g[2], nunion = g[3];
        const double spre = g[4], snext = g[5], sall = g[6], ssim = g[7];
        const double accp = g[8], accn = g[9], nmp = g[10], nmn = g[11];
        const double loss_pre  = (npre > 0.0) ? spre / npre : spre;
        const double loss_next = (nnext > 0.0) ? snext / nnext : snext;
        const double loss      = (npre > 0.0 && nnext > 0.0) ? sall / npre : sall;
        const double loss_sim  = (nunion > 0.0) ? ssim / tnum : ssim;
        const double total = (loss_pre + loss_next + loss + loss_sim) * 0.25;
        const double ap = (nmp > 0.0) ? accp / nmp : accp + 1.0;
        const double an = (nmn > 0.0) ? accn / nmn : accn + 1.0;
        out[0] = (float)loss_pre;
        out[1] = (float)loss_next;
        out[2] = (float)loss_sim;
        out[3] = (float)total;
        out[4] = (float)ap;
        out[5] = (float)an;
        out[6] = (float)((ap + an) * 0.5);
    }
}

extern "C" void kernel_launch(void* const* d_in, const int* in_sizes, int n_in,
                              void* d_out, int out_size, void* d_ws, size_t ws_size,
                              hipStream_t stream) {
    const float* input  = (const float*)d_in[0];
    const int*   target = (const int*)d_in[1];
    const int*   mask0  = (const int*)d_in[2];
    const int*   mask1  = (const int*)d_in[3];
    float* out = (float*)d_out;
    float* part = (float*)d_ws;   // NACC * slices floats, SoA

    const int slices = in_sizes[0] / NEL;  // B*C = 2048

    sst_main<<<slices, 512, 0, stream>>>(input, target, mask0, mask1, out + 7, part, slices);
    sst_final<<<1, 256, 0, stream>>>(part, slices, out);
}